// Round 2
// baseline (175.365 us; speedup 1.0000x reference)
//
#include <hip/hip_runtime.h>

// YOLO-style loss: y_pred (1024,28,28,30) f32, y_true (1024,28,28,5) f32 -> scalar f32.
// Memory-bound: ~112.6 MB read -> ~18us floor at 6.3 TB/s.
// R1 lesson: per-thread strided loads (120B lane stride) are VMEM-transaction-bound
// (64 distinct cache lines per wave instruction). Fix: coalesced float4 staging via LDS.

#define S_GRID 28
#define N_CELLS (1024 * S_GRID * S_GRID)   // 802816
#define CPB 256                             // cells per block == threads per block

__device__ __forceinline__ float iou_calc(float bx, float by, float bw, float bh,
                                          float tx, float ty, float tw, float th,
                                          float gi, float gj) {
    float acx = (gj + bx) * 8.0f;
    float acy = (gi + by) * 8.0f;
    float aw  = bw * 224.0f;
    float ah  = bh * 224.0f;
    float ax1 = acx - aw * 0.5f, ax2 = acx + aw * 0.5f;
    float ay1 = acy - ah * 0.5f, ay2 = acy + ah * 0.5f;
    float bcx = (gj + tx) * 8.0f;
    float bcy = (gi + ty) * 8.0f;
    float btw = tw * 224.0f;
    float bth = th * 224.0f;
    float bx1 = bcx - btw * 0.5f, bx2 = bcx + btw * 0.5f;
    float by1 = bcy - bth * 0.5f, by2 = bcy + bth * 0.5f;

    float iw = fmaxf(fminf(ax2, bx2) - fmaxf(ax1, bx1), 0.0f);
    float ih = fmaxf(fminf(ay2, by2) - fmaxf(ay1, by1), 0.0f);
    float inter = iw * ih;
    float area_a = fmaxf(ax2 - ax1, 0.0f) * fmaxf(ay2 - ay1, 0.0f);
    float area_b = fmaxf(bx2 - bx1, 0.0f) * fmaxf(by2 - by1, 0.0f);
    return inter / (area_a + area_b - inter + 1e-12f);
}

__global__ void zero_out_kernel(float* out) {
    out[0] = 0.0f;
}

__global__ __launch_bounds__(256) void yolo_loss_kernel(const float4* __restrict__ yp4,
                                                        const float4* __restrict__ yt4,
                                                        float* __restrict__ out) {
    // pred: 256 cells x 30 floats, stored with stride 31 (31 mod 32 = -1 -> conflict-free reads)
    __shared__ float sp[CPB * 31];              // 31744 B
    __shared__ __align__(16) float st[CPB * 5]; // 5120 B, stride 5 (coprime 32 -> conflict-free)

    int tid = threadIdx.x;
    int bcell = blockIdx.x * CPB;

    // --- stage y_pred: 256*30 floats = 1920 float4, coalesced ---
    const float4* pb = yp4 + (size_t)blockIdx.x * (CPB * 30 / 4);  // 1920 float4/block
#pragma unroll
    for (int k = 0; k < 8; ++k) {
        int idx = k * 256 + tid;
        if (idx < 1920) {
            float4 v = pb[idx];
            int e = idx * 4;
            float vals[4] = {v.x, v.y, v.z, v.w};
#pragma unroll
            for (int j = 0; j < 4; ++j) {
                int ee = e + j;
                int cell = ee / 30;          // magic-mul
                int rem = ee - cell * 30;
                sp[cell * 31 + rem] = vals[j];
            }
        }
    }

    // --- stage y_true: 256*5 floats = 320 float4, coalesced ---
    const float4* tb = yt4 + (size_t)blockIdx.x * (CPB * 5 / 4);   // 320 float4/block
#pragma unroll
    for (int k = 0; k < 2; ++k) {
        int idx = k * 256 + tid;
        if (idx < 320) {
            ((float4*)st)[idx] = tb[idx];
        }
    }

    __syncthreads();

    // --- compute: one cell per thread, reads from LDS ---
    int c = bcell + tid;
    int ij = c % (S_GRID * S_GRID);
    float gi = (float)(ij / S_GRID);
    float gj = (float)(ij % S_GRID);

    float pr[30];
#pragma unroll
    for (int k = 0; k < 30; ++k) pr[k] = sp[tid * 31 + k];

    float tc = st[tid * 5 + 0];
    float tx = st[tid * 5 + 1];
    float ty = st[tid * 5 + 2];
    float tw = st[tid * 5 + 3];
    float th = st[tid * 5 + 4];

    float iou0 = iou_calc(pr[0], pr[1], pr[2], pr[3], tx, ty, tw, th, gi, gj);
    float iou1 = iou_calc(pr[5], pr[6], pr[7], pr[8], tx, ty, tw, th, gi, gj);
    bool choose1 = !(iou0 > iou1);

    float conf_pred = choose1 ? pr[9] : pr[4];
    float conf_true = choose1 ? iou1 : iou0;
    float xp = choose1 ? pr[5] : pr[0];
    float yp = choose1 ? pr[6] : pr[1];

    float dcf = conf_pred - conf_true;
    float loss_conf_obj = dcf * dcf;

    float d0 = xp - tx, d1 = yp - ty;
    float loss_coord = 5.0f * (d0 * d0 + d1 * d1);

    int cls = (int)tc - 1;   // -1 => one-hot all zeros
    float lcls = 0.0f;
#pragma unroll
    for (int k = 0; k < 20; ++k) {
        float oh = (k == cls) ? 1.0f : 0.0f;
        float d = pr[10 + k] - oh;
        lcls += d * d;
    }

    float loss_noobj = 0.5f * (pr[4] * pr[4] + pr[9] * pr[9]);

    bool obj = (tc != 0.0f);
    float val = obj ? (loss_conf_obj + loss_coord + lcls) : loss_noobj;

    // --- reduction: wave shuffle -> LDS -> one atomic per block ---
#pragma unroll
    for (int off = 32; off > 0; off >>= 1) {
        val += __shfl_down(val, off, 64);
    }
    __shared__ float wsum[4];
    int lane = tid & 63;
    int wid  = tid >> 6;
    if (lane == 0) wsum[wid] = val;
    __syncthreads();
    if (tid == 0) {
        float s = wsum[0] + wsum[1] + wsum[2] + wsum[3];
        atomicAdd(out, s * (1.0f / 1024.0f));
    }
}

extern "C" void kernel_launch(void* const* d_in, const int* in_sizes, int n_in,
                              void* d_out, int out_size, void* d_ws, size_t ws_size,
                              hipStream_t stream) {
    const float4* y_pred = (const float4*)d_in[0];
    const float4* y_true = (const float4*)d_in[1];
    float* out = (float*)d_out;

    zero_out_kernel<<<1, 1, 0, stream>>>(out);
    int blocks = N_CELLS / CPB;  // 3136, exact
    yolo_loss_kernel<<<blocks, 256, 0, stream>>>(y_pred, y_true, out);
}

// Round 3
// 158.047 us; speedup vs baseline: 1.1096x; 1.1096x over previous
//
#include <hip/hip_runtime.h>

// YOLO-style loss: y_pred (1024,28,28,30) f32, y_true (1024,28,28,5) f32 -> scalar f32.
// ~113 MB read, memory-bound floor ~18us at 6.3 TB/s (less if L3-warm).
// R1: per-thread strided loads -> VMEM-transaction-bound, ~55us.
// R2: full LDS staging + 3136 same-address atomicAdds -> 65us, all pipes idle.
// R3 theory: same-address atomic serialization was the common ~55-65us floor.
//   -> per-block partials in d_ws + tail reduce kernel (no atomics, no zero-kernel)
//   -> class/noobj terms computed inline in the streaming pass (LDS 37KB->16.4KB, 8 blocks/CU)
//   -> all 10 global float4 loads hoisted (full memory-level parallelism)

#define S_GRID 28
#define N_CELLS (1024 * S_GRID * S_GRID)   // 802816
#define CPB 256                             // cells per block == threads per block
#define NBLOCKS (N_CELLS / CPB)             // 3136

__device__ __forceinline__ float iou_calc(float bx, float by, float bw, float bh,
                                          float tx, float ty, float tw, float th,
                                          float gi, float gj) {
    float acx = (gj + bx) * 8.0f;
    float acy = (gi + by) * 8.0f;
    float aw  = bw * 224.0f;
    float ah  = bh * 224.0f;
    float ax1 = acx - aw * 0.5f, ax2 = acx + aw * 0.5f;
    float ay1 = acy - ah * 0.5f, ay2 = acy + ah * 0.5f;
    float bcx = (gj + tx) * 8.0f;
    float bcy = (gi + ty) * 8.0f;
    float btw = tw * 224.0f;
    float bth = th * 224.0f;
    float bx1 = bcx - btw * 0.5f, bx2 = bcx + btw * 0.5f;
    float by1 = bcy - bth * 0.5f, by2 = bcy + bth * 0.5f;

    float iw = fmaxf(fminf(ax2, bx2) - fmaxf(ax1, bx1), 0.0f);
    float ih = fmaxf(fminf(ay2, by2) - fmaxf(ay1, by1), 0.0f);
    float inter = iw * ih;
    float area_a = fmaxf(ax2 - ax1, 0.0f) * fmaxf(ay2 - ay1, 0.0f);
    float area_b = fmaxf(bx2 - bx1, 0.0f) * fmaxf(by2 - by1, 0.0f);
    return inter / (area_a + area_b - inter + 1e-12f);
}

__global__ __launch_bounds__(256) void yolo_loss_kernel(const float4* __restrict__ yp4,
                                                        const float4* __restrict__ yt4,
                                                        float* __restrict__ partials) {
    // ch 0..9 of each cell, stride 11 (coprime with 32 -> conflict-free)
    __shared__ float sp[CPB * 11];              // 11264 B
    __shared__ __align__(16) float st[CPB * 5]; // 5120 B, stride 5 (coprime with 32)
    __shared__ float wsum[4];

    int tid = threadIdx.x;

    // ---- hoist ALL global loads (10 float4 in flight) ----
    const float4* tb = yt4 + (size_t)blockIdx.x * 320;
    float4 vt0 = tb[tid];                                        // 256 < 320: all valid
    float4 vt1 = (tid < 64) ? tb[256 + tid] : make_float4(0, 0, 0, 0);

    const float4* pb = yp4 + (size_t)blockIdx.x * 1920;
    float4 vp[8];
#pragma unroll
    for (int k = 0; k < 8; ++k) {
        int idx = k * 256 + tid;
        vp[k] = (idx < 1920) ? pb[idx] : make_float4(0, 0, 0, 0);
    }

    // ---- stage y_true ----
    ((float4*)st)[tid] = vt0;
    if (tid < 64) ((float4*)st)[256 + tid] = vt1;
    __syncthreads();

    // ---- streaming pass over y_pred: class + noobj terms inline, scatter ch0..9 ----
    float acc = 0.0f;
#pragma unroll
    for (int k = 0; k < 8; ++k) {
        int idx = k * 256 + tid;
        if (idx < 1920) {
            float vals[4] = {vp[k].x, vp[k].y, vp[k].z, vp[k].w};
            int e0 = idx * 4;
#pragma unroll
            for (int j = 0; j < 4; ++j) {
                int ee = e0 + j;
                int lcell = ee / 30;
                int ch = ee - lcell * 30;
                float tc = st[lcell * 5];          // broadcast-friendly
                bool obj = (tc != 0.0f);
                float v = vals[j];
                if (ch >= 10) {
                    int cls = (int)tc - 1;
                    float oh = (ch - 10 == cls) ? 1.0f : 0.0f;
                    float d = v - oh;
                    acc += obj ? d * d : 0.0f;
                } else {
                    sp[lcell * 11 + ch] = v;
                    if (ch == 4 || ch == 9) {
                        acc += obj ? 0.0f : 0.5f * v * v;
                    }
                }
            }
        }
    }
    __syncthreads();

    // ---- per-cell pass: IoU / conf / coord ----
    {
        int c = blockIdx.x * CPB + tid;
        int ij = c % (S_GRID * S_GRID);
        float gi = (float)(ij / S_GRID);
        float gj = (float)(ij % S_GRID);

        float p0 = sp[tid * 11 + 0], p1 = sp[tid * 11 + 1];
        float p2 = sp[tid * 11 + 2], p3 = sp[tid * 11 + 3];
        float p4 = sp[tid * 11 + 4], p5 = sp[tid * 11 + 5];
        float p6 = sp[tid * 11 + 6], p7 = sp[tid * 11 + 7];
        float p8 = sp[tid * 11 + 8], p9 = sp[tid * 11 + 9];

        float tc = st[tid * 5 + 0];
        float tx = st[tid * 5 + 1];
        float ty = st[tid * 5 + 2];
        float tw = st[tid * 5 + 3];
        float th = st[tid * 5 + 4];

        if (tc != 0.0f) {
            float iou0 = iou_calc(p0, p1, p2, p3, tx, ty, tw, th, gi, gj);
            float iou1 = iou_calc(p5, p6, p7, p8, tx, ty, tw, th, gi, gj);
            bool choose1 = !(iou0 > iou1);

            float conf_pred = choose1 ? p9 : p4;
            float conf_true = choose1 ? iou1 : iou0;
            float xp = choose1 ? p5 : p0;
            float yp = choose1 ? p6 : p1;

            float dcf = conf_pred - conf_true;
            float d0 = xp - tx, d1 = yp - ty;
            acc += dcf * dcf + 5.0f * (d0 * d0 + d1 * d1);
        }
    }

    // ---- block reduction -> one partial per block (no atomics) ----
#pragma unroll
    for (int off = 32; off > 0; off >>= 1) {
        acc += __shfl_down(acc, off, 64);
    }
    int lane = tid & 63;
    int wid  = tid >> 6;
    if (lane == 0) wsum[wid] = acc;
    __syncthreads();
    if (tid == 0) {
        partials[blockIdx.x] = wsum[0] + wsum[1] + wsum[2] + wsum[3];
    }
}

__global__ __launch_bounds__(256) void reduce_kernel(const float* __restrict__ partials,
                                                     float* __restrict__ out) {
    int tid = threadIdx.x;
    float s = 0.0f;
#pragma unroll
    for (int k = 0; k < 13; ++k) {
        int i = k * 256 + tid;
        if (i < NBLOCKS) s += partials[i];
    }
#pragma unroll
    for (int off = 32; off > 0; off >>= 1) {
        s += __shfl_down(s, off, 64);
    }
    __shared__ float wsum[4];
    int lane = tid & 63;
    int wid  = tid >> 6;
    if (lane == 0) wsum[wid] = s;
    __syncthreads();
    if (tid == 0) {
        out[0] = (wsum[0] + wsum[1] + wsum[2] + wsum[3]) * (1.0f / 1024.0f);
    }
}

extern "C" void kernel_launch(void* const* d_in, const int* in_sizes, int n_in,
                              void* d_out, int out_size, void* d_ws, size_t ws_size,
                              hipStream_t stream) {
    const float4* y_pred = (const float4*)d_in[0];
    const float4* y_true = (const float4*)d_in[1];
    float* out = (float*)d_out;
    float* partials = (float*)d_ws;   // 3136 floats, fully overwritten each call

    yolo_loss_kernel<<<NBLOCKS, 256, 0, stream>>>(y_pred, y_true, partials);
    reduce_kernel<<<1, 256, 0, stream>>>(partials, out);
}

// Round 4
// 153.149 us; speedup vs baseline: 1.1451x; 1.0320x over previous
//
#include <hip/hip_runtime.h>

// YOLO-style loss: y_pred (1024,28,28,30) f32, y_true (1024,28,28,5) f32 -> scalar f32.
// ~113 MB read; L3 absorbs ~half (R2 FETCH_SIZE = 56 MB) -> floor ~10-18us.
// R1: per-thread strided loads -> VMEM-transaction-bound (~51us).
// R2: LDS scatter staging + same-address atomics -> 65us, all pipes idle.
// R3: partials (no atomics) + inline streaming class terms -> ~45us.
// R4: global_load_lds(16B) raw staging (no scatter math, no VGPR roundtrip),
//     CPB=128 (LDS 17.9KB, 8 blocks/CU), all per-cell math in registers, branch-free.

#define S_GRID 28
#define N_CELLS (1024 * S_GRID * S_GRID)   // 802816
#define CPB 128                             // cells per block == threads per block
#define NBLOCKS (N_CELLS / CPB)             // 6272

typedef const __attribute__((address_space(1))) unsigned int* gptr_t;
typedef __attribute__((address_space(3))) unsigned int* lptr_t;

__device__ __forceinline__ float iou_calc(float bx, float by, float bw, float bh,
                                          float tx, float ty, float tw, float th,
                                          float gi, float gj) {
    float acx = (gj + bx) * 8.0f;
    float acy = (gi + by) * 8.0f;
    float aw  = bw * 224.0f;
    float ah  = bh * 224.0f;
    float ax1 = acx - aw * 0.5f, ax2 = acx + aw * 0.5f;
    float ay1 = acy - ah * 0.5f, ay2 = acy + ah * 0.5f;
    float bcx = (gj + tx) * 8.0f;
    float bcy = (gi + ty) * 8.0f;
    float btw = tw * 224.0f;
    float bth = th * 224.0f;
    float bx1 = bcx - btw * 0.5f, bx2 = bcx + btw * 0.5f;
    float by1 = bcy - bth * 0.5f, by2 = bcy + bth * 0.5f;

    float iw = fmaxf(fminf(ax2, bx2) - fmaxf(ax1, bx1), 0.0f);
    float ih = fmaxf(fminf(ay2, by2) - fmaxf(ay1, by1), 0.0f);
    float inter = iw * ih;
    float area_a = fmaxf(ax2 - ax1, 0.0f) * fmaxf(ay2 - ay1, 0.0f);
    float area_b = fmaxf(bx2 - bx1, 0.0f) * fmaxf(by2 - by1, 0.0f);
    return inter / (area_a + area_b - inter + 1e-12f);
}

__global__ __launch_bounds__(128) void yolo_loss_kernel(const float4* __restrict__ yp4,
                                                        const float4* __restrict__ yt4,
                                                        float* __restrict__ partials) {
    __shared__ float sp[CPB * 30];               // 15360 B, raw cell-major (matches global)
    __shared__ __align__(16) float st[CPB * 5];  // 2560 B, stride 5 (coprime 32)
    __shared__ float wsum[2];

    int tid  = threadIdx.x;
    int lane = tid & 63;
    int wave = tid >> 6;

    // ---- stage y_pred: 960 float4 = 15 chunks of 1024B, async direct-to-LDS ----
    const float4* pb = yp4 + (size_t)blockIdx.x * (CPB * 30 / 4);
#pragma unroll
    for (int k = 0; k < 8; ++k) {
        int c = k * 2 + wave;
        if (c < 15) {
            const float4* src = pb + c * 64 + lane;            // per-lane global addr
            __builtin_amdgcn_global_load_lds((gptr_t)src,
                                             (lptr_t)(sp + c * 256),  // wave-uniform base
                                             16, 0, 0);
        }
    }

    // ---- stage y_true: 160 float4, plain coalesced copy ----
    const float4* tb = yt4 + (size_t)blockIdx.x * (CPB * 5 / 4);
    float4 v0 = tb[tid];                                       // 128 < 160: all valid
    float4 v1 = (tid < 32) ? tb[128 + tid] : make_float4(0, 0, 0, 0);
    ((float4*)st)[tid] = v0;
    if (tid < 32) ((float4*)st)[128 + tid] = v1;

    __syncthreads();   // drains vmcnt (incl. global_load_lds) + lgkm

    // ---- per-cell compute, all in registers, branch-free select ----
    int c = blockIdx.x * CPB + tid;
    int ij = c % (S_GRID * S_GRID);
    float gi = (float)(ij / S_GRID);
    float gj = (float)(ij % S_GRID);

    float pr[30];
    const float* p = sp + tid * 30;
#pragma unroll
    for (int k = 0; k < 30; ++k) pr[k] = p[k];

    float tc = st[tid * 5 + 0];
    float tx = st[tid * 5 + 1];
    float ty = st[tid * 5 + 2];
    float tw = st[tid * 5 + 3];
    float th = st[tid * 5 + 4];

    float iou0 = iou_calc(pr[0], pr[1], pr[2], pr[3], tx, ty, tw, th, gi, gj);
    float iou1 = iou_calc(pr[5], pr[6], pr[7], pr[8], tx, ty, tw, th, gi, gj);
    bool choose1 = !(iou0 > iou1);

    float conf_pred = choose1 ? pr[9] : pr[4];
    float conf_true = choose1 ? iou1 : iou0;
    float xp = choose1 ? pr[5] : pr[0];
    float yp = choose1 ? pr[6] : pr[1];

    float dcf = conf_pred - conf_true;
    float d0 = xp - tx, d1 = yp - ty;

    int cls = (int)tc - 1;   // -1 => one-hot all zeros
    float lcls = 0.0f;
#pragma unroll
    for (int k = 0; k < 20; ++k) {
        float oh = (k == cls) ? 1.0f : 0.0f;
        float d = pr[10 + k] - oh;
        lcls += d * d;
    }

    float obj_loss   = dcf * dcf + 5.0f * (d0 * d0 + d1 * d1) + lcls;
    float noobj_loss = 0.5f * (pr[4] * pr[4] + pr[9] * pr[9]);
    float val = (tc != 0.0f) ? obj_loss : noobj_loss;

    // ---- reduction: wave shuffle -> LDS -> one partial per block ----
#pragma unroll
    for (int off = 32; off > 0; off >>= 1) {
        val += __shfl_down(val, off, 64);
    }
    if (lane == 0) wsum[wave] = val;
    __syncthreads();
    if (tid == 0) {
        partials[blockIdx.x] = wsum[0] + wsum[1];
    }
}

__global__ __launch_bounds__(256) void reduce_kernel(const float* __restrict__ partials,
                                                     float* __restrict__ out) {
    int tid = threadIdx.x;
    float s = 0.0f;
#pragma unroll
    for (int k = 0; k < 25; ++k) {
        int i = k * 256 + tid;
        if (i < NBLOCKS) s += partials[i];
    }
#pragma unroll
    for (int off = 32; off > 0; off >>= 1) {
        s += __shfl_down(s, off, 64);
    }
    __shared__ float wsum[4];
    int lane = tid & 63;
    int wid  = tid >> 6;
    if (lane == 0) wsum[wid] = s;
    __syncthreads();
    if (tid == 0) {
        out[0] = (wsum[0] + wsum[1] + wsum[2] + wsum[3]) * (1.0f / 1024.0f);
    }
}

extern "C" void kernel_launch(void* const* d_in, const int* in_sizes, int n_in,
                              void* d_out, int out_size, void* d_ws, size_t ws_size,
                              hipStream_t stream) {
    const float4* y_pred = (const float4*)d_in[0];
    const float4* y_true = (const float4*)d_in[1];
    float* out = (float*)d_out;
    float* partials = (float*)d_ws;   // 6272 floats, fully overwritten each call

    yolo_loss_kernel<<<NBLOCKS, CPB, 0, stream>>>(y_pred, y_true, partials);
    reduce_kernel<<<1, 256, 0, stream>>>(partials, out);
}

// Round 5
// 151.089 us; speedup vs baseline: 1.1607x; 1.0136x over previous
//
#include <hip/hip_runtime.h>

// YOLO-style loss: y_pred (1024,28,28,30) f32, y_true (1024,28,28,5) f32 -> scalar f32.
// ~113 MB read; L3 absorbs ~half (FETCH_SIZE 56 MB) -> floor ~10-15us.
// R1: per-thread strided loads -> VMEM-transaction-bound (~55us).
// R2: LDS scatter + same-address atomics -> 65us.
// R3: partials + inline streaming -> ~45us.  R4: global_load_lds staging -> ~40us.
// R3/R4 lesson: throughput pipes all idle; limiter is the barrier-drain structure
// (tiny blocks, 2x __syncthreads, all waves stall on slowest cold-miss load).
// R5: BARRIER-FREE wave-private staging. Each wave owns a 64-cell tile + private
// LDS slab; coalesced float2 loads -> conflict-free ds_write (raw layout) ->
// stride-30 reads (4-way, ~free). y_true loaded directly per-lane (L1 line reuse).
// No __syncthreads in main kernel; waves fully independent; 1 partial per wave.

#define S_GRID 28
#define N_CELLS (1024 * S_GRID * S_GRID)     // 802816
#define CPW 64                               // cells per wave
#define WPB 4                                // waves per block
#define BLOCK (WPB * 64)                     // 256
#define N_WAVES (N_CELLS / CPW)              // 12544
#define NBLOCKS (N_WAVES / WPB)              // 3136

__device__ __forceinline__ float iou_calc(float bx, float by, float bw, float bh,
                                          float tx, float ty, float tw, float th,
                                          float gi, float gj) {
    float acx = (gj + bx) * 8.0f;
    float acy = (gi + by) * 8.0f;
    float aw  = bw * 224.0f;
    float ah  = bh * 224.0f;
    float ax1 = acx - aw * 0.5f, ax2 = acx + aw * 0.5f;
    float ay1 = acy - ah * 0.5f, ay2 = acy + ah * 0.5f;
    float bcx = (gj + tx) * 8.0f;
    float bcy = (gi + ty) * 8.0f;
    float btw = tw * 224.0f;
    float bth = th * 224.0f;
    float bx1 = bcx - btw * 0.5f, bx2 = bcx + btw * 0.5f;
    float by1 = bcy - bth * 0.5f, by2 = bcy + bth * 0.5f;

    float iw = fmaxf(fminf(ax2, bx2) - fmaxf(ax1, bx1), 0.0f);
    float ih = fmaxf(fminf(ay2, by2) - fmaxf(ay1, by1), 0.0f);
    float inter = iw * ih;
    float area_a = fmaxf(ax2 - ax1, 0.0f) * fmaxf(ay2 - ay1, 0.0f);
    float area_b = fmaxf(bx2 - bx1, 0.0f) * fmaxf(by2 - by1, 0.0f);
    return inter / (area_a + area_b - inter + 1e-12f);
}

__global__ __launch_bounds__(BLOCK, 4) void yolo_loss_kernel(const float2* __restrict__ yp2,
                                                             const float* __restrict__ yt,
                                                             float* __restrict__ partials) {
    // wave-private pred slabs, raw (global) layout: 64 cells x 30 floats = 7680 B each
    __shared__ float sp[WPB][CPW * 30];

    int tid  = threadIdx.x;
    int lane = tid & 63;
    int wave = tid >> 6;
    int gwave = blockIdx.x * WPB + wave;     // global wave id = tile id

    // ---- stage y_pred tile: 1920 floats = 960 float2; 15 float2/lane, lane-major
    // each wave instruction covers 512 B contiguous -> fully coalesced ----
    const float2* pb = yp2 + (size_t)gwave * (CPW * 30 / 2);   // 960 float2 per wave
    float2 v[15];
#pragma unroll
    for (int k = 0; k < 15; ++k) v[k] = pb[k * 64 + lane];

    // raw layout: float2 index == LDS float2 index -> lane-contiguous, conflict-free
    float2* spw2 = (float2*)sp[wave];
#pragma unroll
    for (int k = 0; k < 15; ++k) spw2[k * 64 + lane] = v[k];

    // ---- y_true: each lane needs only its own cell's 5 floats; direct loads,
    // L1 serves the repeated line touches (no cross-lane use -> no staging) ----
    int cell = gwave * CPW + lane;
    const float* t = yt + (size_t)cell * 5;
    float tc = t[0], tx = t[1], ty = t[2], tw = t[3], th = t[4];

    // ---- read back own cell's 30 channels (stride 30: 4 lanes/bank, ~free) ----
    float pr[30];
    const float* p = sp[wave] + lane * 30;
#pragma unroll
    for (int k = 0; k < 30; ++k) pr[k] = p[k];

    // ---- per-cell loss, branch-free select ----
    int ij = cell % (S_GRID * S_GRID);
    float gi = (float)(ij / S_GRID);
    float gj = (float)(ij % S_GRID);

    float iou0 = iou_calc(pr[0], pr[1], pr[2], pr[3], tx, ty, tw, th, gi, gj);
    float iou1 = iou_calc(pr[5], pr[6], pr[7], pr[8], tx, ty, tw, th, gi, gj);
    bool choose1 = !(iou0 > iou1);

    float conf_pred = choose1 ? pr[9] : pr[4];
    float conf_true = choose1 ? iou1 : iou0;
    float xp = choose1 ? pr[5] : pr[0];
    float yp = choose1 ? pr[6] : pr[1];

    float dcf = conf_pred - conf_true;
    float d0 = xp - tx, d1 = yp - ty;

    int cls = (int)tc - 1;   // -1 => one-hot all zeros
    float lcls = 0.0f;
#pragma unroll
    for (int k = 0; k < 20; ++k) {
        float oh = (k == cls) ? 1.0f : 0.0f;
        float d = pr[10 + k] - oh;
        lcls += d * d;
    }

    float obj_loss   = dcf * dcf + 5.0f * (d0 * d0 + d1 * d1) + lcls;
    float noobj_loss = 0.5f * (pr[4] * pr[4] + pr[9] * pr[9]);
    float val = (tc != 0.0f) ? obj_loss : noobj_loss;

    // ---- wave-local reduction only; one partial per wave, NO barrier ----
#pragma unroll
    for (int off = 32; off > 0; off >>= 1) {
        val += __shfl_down(val, off, 64);
    }
    if (lane == 0) partials[gwave] = val;
}

__global__ __launch_bounds__(256) void reduce_kernel(const float* __restrict__ partials,
                                                     float* __restrict__ out) {
    int tid = threadIdx.x;
    float s = 0.0f;
#pragma unroll
    for (int k = 0; k < 49; ++k) {          // 49 * 256 = 12544 exact
        s += partials[k * 256 + tid];
    }
#pragma unroll
    for (int off = 32; off > 0; off >>= 1) {
        s += __shfl_down(s, off, 64);
    }
    __shared__ float wsum[4];
    int lane = tid & 63;
    int wid  = tid >> 6;
    if (lane == 0) wsum[wid] = s;
    __syncthreads();
    if (tid == 0) {
        out[0] = (wsum[0] + wsum[1] + wsum[2] + wsum[3]) * (1.0f / 1024.0f);
    }
}

extern "C" void kernel_launch(void* const* d_in, const int* in_sizes, int n_in,
                              void* d_out, int out_size, void* d_ws, size_t ws_size,
                              hipStream_t stream) {
    const float2* y_pred = (const float2*)d_in[0];
    const float*  y_true = (const float*)d_in[1];
    float* out = (float*)d_out;
    float* partials = (float*)d_ws;   // 12544 floats, fully overwritten each call

    yolo_loss_kernel<<<NBLOCKS, BLOCK, 0, stream>>>(y_pred, y_true, partials);
    reduce_kernel<<<1, 256, 0, stream>>>(partials, out);
}